// Round 11
// baseline (166.211 us; speedup 1.0000x reference)
//
#include <hip/hip_runtime.h>
#include <hip/hip_bf16.h>

#define HP    66
#define QTOT  (HP*HP)          // 4356
#define LSTR  67               // padded LDS row stride
#define NWIN  29
#define NW    (NWIN*NWIN)      // 841
#define NWP   844              // padded w-stride (divisible by 4)
#define NG    211              // NWP/4 groups per k
#define KK    7
#define WOFF2 14
#define NZ    15               // dy-chunks for contraction
#define QB    8                // queries per k_weights block
#define QBN   545              // ceil(QTOT/8)
#define NIT   27               // ceil(841/32)
#define NSEG3 198              // 66 lines x 3 segments of 22

// ws float layout:
// 0        : yex    [QTOT][8] interleaved f32
// 8*QTOT   : xex    [QTOT][8] interleaved f32
// 16*QTOT  : x66i   [QTOT][8] interleaved f32
// 24*QTOT  : sqye   QTOT
// 25*QTOT  : sqxe   QTOT
// 26*QTOT  : lt66   QTOT
// 27*QTOT  : n2q    QTOT
// 28*QTOT  : n2db   QTOT
// 29*QTOT  : ltb    QTOT
// 30*QTOT  : dist   NW*QTOT f32      (reused as accb2 after k_weights)
// 30*QTOT + NW*QTOT : wf  bf16 [k][qb][NWP][8q]

__global__ __launch_bounds__(256) void k_prep1(const float* __restrict__ x,
    const float* __restrict__ xe, const float* __restrict__ ye,
    const float* __restrict__ lt, float* __restrict__ ws) {
  int p = blockIdx.x * 256 + threadIdx.x;
  if (p >= QTOT) return;
  int i = p / HP, j = p % HP;
  bool in = (i >= 1 && i < HP-1 && j >= 1 && j < HP-1);
  int src = (i-1)*64 + (j-1);
  float vy[8], vx[8], vv[8];
  float sy = 0.f, sx = 0.f;
#pragma unroll
  for (int e = 0; e < 8; ++e) {
    vy[e] = in ? ye[e*4096 + src] : 0.f;
    vx[e] = in ? xe[e*4096 + src] : 0.f;
    vv[e] = in ? x [e*4096 + src] : 0.f;
    sy += vy[e]*vy[e]; sx += vx[e]*vx[e];
  }
  float4* yp = (float4*)(ws + (size_t)p*8);
  float4* xp = (float4*)(ws + 8*QTOT + (size_t)p*8);
  float4* vp = (float4*)(ws + 16*QTOT + (size_t)p*8);
  yp[0] = make_float4(vy[0], vy[1], vy[2], vy[3]);
  yp[1] = make_float4(vy[4], vy[5], vy[6], vy[7]);
  xp[0] = make_float4(vx[0], vx[1], vx[2], vx[3]);
  xp[1] = make_float4(vx[4], vx[5], vx[6], vx[7]);
  vp[0] = make_float4(vv[0], vv[1], vv[2], vv[3]);
  vp[1] = make_float4(vv[4], vv[5], vv[6], vv[7]);
  ws[24*QTOT + p] = sy;
  ws[25*QTOT + p] = sx;
  ws[26*QTOT + p] = in ? lt[src] : 0.f;
}

__global__ __launch_bounds__(256) void k_prep2(float* __restrict__ ws) {
  int p = blockIdx.x * 256 + threadIdx.x;
  if (p >= QTOT) return;
  int i = p / HP, j = p % HP;
  const float* sqye = ws + 24*QTOT;
  const float* sqxe = ws + 25*QTOT;
  const float* lt66 = ws + 26*QTOT;
  float a = 0.f, b = 0.f, c = 0.f;
  for (int u = -5; u <= 4; ++u) {
    int ii = i + u; if (ii < 0 || ii >= HP) continue;
    for (int v = -5; v <= 4; ++v) {
      int jj = j + v; if (jj < 0 || jj >= HP) continue;
      int o = ii*HP + jj;
      a += sqye[o]; b += sqxe[o]; c += lt66[o];
    }
  }
  ws[27*QTOT + p] = a;
  ws[28*QTOT + p] = b;
  ws[29*QTOT + p] = c * 0.01f;
}

// one block per shift w: dist plane [w][q]; vectorized interleaved staging;
// register-rotation sliding box [-5,+4]
__global__ __launch_bounds__(256) void k_dist(const float* __restrict__ ws,
                                              float* __restrict__ dist) {
  __shared__ float s[HP*LSTR];
  __shared__ float h[HP*LSTR];
  int w = blockIdx.x, tid = threadIdx.x;
  int dy = w / NWIN - WOFF2, dx = w % NWIN - WOFF2;
  const float* yex = ws;
  const float* xex = ws + 8*QTOT;
  const float* n2q  = ws + 27*QTOT;
  const float* n2db = ws + 28*QTOT;
  for (int p = tid; p < QTOT; p += 256) {
    int i = p / HP, j = p % HP;
    int ii = i + dy, jj = j + dx;
    float sv = 0.f;
    if (ii >= 0 && ii < HP && jj >= 0 && jj < HP) {
      int p2 = ii*HP + jj;
      const float4* yp = (const float4*)(yex + (size_t)p*8);
      const float4* xp = (const float4*)(xex + (size_t)p2*8);
      float4 a0 = yp[0], a1 = yp[1], b0 = xp[0], b1 = xp[1];
      sv += a0.x*b0.x; sv += a0.y*b0.y; sv += a0.z*b0.z; sv += a0.w*b0.w;
      sv += a1.x*b1.x; sv += a1.y*b1.y; sv += a1.z*b1.z; sv += a1.w*b1.w;
    }
    s[i*LSTR + j] = sv;
  }
  __syncthreads();
  if (tid < NSEG3) {
    int row = tid % HP, seg = tid / HP, c0 = seg*22;
    const float* ar = s + row*LSTR;
    float* hr = h + row*LSTR;
    float w9[9]; float sum = 0.f;
#pragma unroll
    for (int t = 0; t < 9; ++t) {
      int jj = c0 - 5 + t;
      float v = (jj >= 0) ? ar[jj] : 0.f;
      w9[t] = v; sum += v;
    }
#pragma unroll
    for (int t = 0; t < 22; ++t) {
      int j = c0 + t, jn = j + 4;
      float nv = (jn < HP) ? ar[jn] : 0.f;
      sum += nv;
      hr[j] = sum;
      sum -= w9[t % 9];
      w9[t % 9] = nv;
    }
  }
  __syncthreads();
  if (tid < NSEG3) {
    int col = tid % HP, seg = tid / HP, r0 = seg*22;
    float w9[9]; float sum = 0.f;
#pragma unroll
    for (int t = 0; t < 9; ++t) {
      int ii = r0 - 5 + t;
      float v = (ii >= 0) ? h[ii*LSTR + col] : 0.f;
      w9[t] = v; sum += v;
    }
#pragma unroll
    for (int t = 0; t < 22; ++t) {
      int i = r0 + t, in2 = i + 4;
      float nv = (in2 < HP) ? h[in2*LSTR + col] : 0.f;
      sum += nv;
      float cr = sum;
      int p = i*HP + col;
      int ii = i + dy, jj = col + dx;
      bool valid = (ii >= 0 && ii < HP && jj >= 0 && jj < HP);
      float dv = 1e10f;
      if (valid && !(dy == 0 && dx == 0))
        dv = n2q[p] + n2db[ii*HP + jj] - 2.f * cr;
      dist[w*QTOT + p] = dv;
      sum -= w9[t % 9];
      w9[t % 9] = nv;
    }
  }
}

// 8 queries/block; lv[] only; writes wf[k][qb][w][8q] (NWP stride),
// zeros the w=841..843 padding columns for determinism
__global__ __launch_bounds__(256) void k_weights(const float* __restrict__ ws,
    const float* __restrict__ dist, __hip_bfloat16* __restrict__ wf) {
  __shared__ float mh[32], sh[32];
  int tid = threadIdx.x;
  int qq = tid & (QB-1);
  int qb = blockIdx.x;
  int q = qb * QB + qq;
  bool qok = q < QTOT;
  int qs = qok ? q : (QTOT - 1);
  int wg = tid >> 3;             // 0..31
  int wave = tid >> 6;           // 0..3
  if (tid < 24) {
    int wp2 = NW + (tid >> 3), q2 = tid & 7;
#pragma unroll
    for (int k = 0; k < KK; ++k)
      wf[(((size_t)k*QBN + qb)*NWP + wp2)*8 + q2] = __float2bfloat16(0.f);
  }
  float invT = __expf(-ws[29*QTOT + qs]);
  float lv[NIT];
#pragma unroll
  for (int it = 0; it < NIT; ++it) {
    int w = wg + it*32;
    lv[it] = (qok && w < NW) ? (-dist[w*QTOT + qs] * invT) : -3.0e38f;
  }
  for (int k = 0; k < KK; ++k) {
    float pm = -3.0e38f;
#pragma unroll
    for (int it = 0; it < NIT; ++it) pm = fmaxf(pm, lv[it]);
    pm = fmaxf(pm, __shfl_xor(pm, 8, 64));
    pm = fmaxf(pm, __shfl_xor(pm, 16, 64));
    pm = fmaxf(pm, __shfl_xor(pm, 32, 64));
    if ((tid & 63) < QB) mh[wave*QB + qq] = pm;
    __syncthreads();
    float m = fmaxf(fmaxf(mh[qq], mh[QB+qq]), fmaxf(mh[2*QB+qq], mh[3*QB+qq]));
    float psum = 0.f;
#pragma unroll
    for (int it = 0; it < NIT; ++it) psum += __expf(lv[it] - m);
    psum += __shfl_xor(psum, 8, 64);
    psum += __shfl_xor(psum, 16, 64);
    psum += __shfl_xor(psum, 32, 64);
    if ((tid & 63) < QB) sh[wave*QB + qq] = psum;
    __syncthreads();
    float invden = 1.0f / (sh[qq] + sh[QB+qq] + sh[2*QB+qq] + sh[3*QB+qq]);
    size_t bkq = ((size_t)k*QBN + qb)*NWP;
#pragma unroll
    for (int it = 0; it < NIT; ++it) {
      int w = wg + it*32;
      if (qok && w < NW) {
        float wgt = __expf(lv[it] - m) * invden;
        wf[(bkq + w)*8 + qq] = __float2bfloat16(wgt);
        if (k < KK-1 && wgt > 1e-9f)
          lv[it] += __logf(fmaxf(1.f - wgt, 1e-6f));
      }
    }
    __syncthreads();
  }
}

// one 256t block per (k, 4-w-group): fully coalesced 64B-line plane I/O;
// 4 planes box-filtered sequentially sharing one f32 h buffer
__global__ __launch_bounds__(256) void k_boxw(__hip_bfloat16* __restrict__ wfp) {
  __shared__ uint4 au4[4][546];         // 4 flat bf16[4368] plane stagings
  __shared__ float h[QTOT];             // flat f32 [i*66+j]
  int bid = blockIdx.x;
  int k = bid / NG, g = bid % NG;
  int w0 = g * 4;
  uint4* u4 = (uint4*)wfp;              // one uint4 = 8 bf16 (one qb fragment)
  size_t pb = ((size_t)k*QBN)*NWP + w0;
  int tid = threadIdx.x;
  // phase 1: coalesced gather (consecutive lanes -> consecutive 16B)
  for (int idx = tid; idx < QBN*4; idx += 256) {
    int qb = idx >> 2, wl = idx & 3;
    au4[wl][qb] = u4[pb + (size_t)qb*NWP + wl];
  }
  if (tid < 48) {                       // zero junk tail shorts 4356..4367
    int pl = tid / 12, e = tid % 12;
    ((unsigned short*)au4[pl])[4356 + e] = 0;
  }
  __syncthreads();
#pragma unroll
  for (int pl = 0; pl < 4; ++pl) {
    const unsigned short* a16 = (const unsigned short*)au4[pl];
    if (tid < NSEG3) {                  // horizontal box [-4,+5]
      int row = tid % HP, seg = tid / HP, c0 = seg*22;
      const unsigned short* ar = a16 + row*HP;
      float* hr = h + row*HP;
      float w9[9]; float sum = 0.f;
#pragma unroll
      for (int t = 0; t < 9; ++t) {
        int jj = c0 - 4 + t;
        float v = (jj >= 0) ? __uint_as_float((unsigned)ar[jj] << 16) : 0.f;
        w9[t] = v; sum += v;
      }
#pragma unroll
      for (int t = 0; t < 22; ++t) {
        int j = c0 + t, jn = j + 5;
        float nv = (jn < HP) ? __uint_as_float((unsigned)ar[jn] << 16) : 0.f;
        sum += nv;
        hr[j] = sum;
        sum -= w9[t % 9];
        w9[t % 9] = nv;
      }
    }
    __syncthreads();
    unsigned short* a16w = (unsigned short*)au4[pl];
    if (tid < NSEG3) {                  // vertical box [-4,+5]
      int col = tid % HP, seg = tid / HP, r0 = seg*22;
      float w9[9]; float sum = 0.f;
#pragma unroll
      for (int t = 0; t < 9; ++t) {
        int ii = r0 - 4 + t;
        float v = (ii >= 0) ? h[ii*HP + col] : 0.f;
        w9[t] = v; sum += v;
      }
#pragma unroll
      for (int t = 0; t < 22; ++t) {
        int i = r0 + t, in2 = i + 5;
        float nv = (in2 < HP) ? h[in2*HP + col] : 0.f;
        sum += nv;
        a16w[i*HP + col] = __bfloat16_as_ushort(__float2bfloat16(sum));
        sum -= w9[t % 9];
        w9[t % 9] = nv;
      }
    }
    __syncthreads();
  }
  // phase 4: coalesced scatter back
  for (int idx = tid; idx < QBN*4; idx += 256) {
    int qb = idx >> 2, wl = idx & 3;
    u4[pb + (size_t)qb*NWP + wl] = au4[wl][qb];
  }
}

// grid (16 tiles, NZ, KK): per dd-row, 29 batched ushort loads with immediate
// offsets, then 29 x (2 ds_read_b128 + 8 FMA); xt [r][cc][8] c-contiguous
__global__ __launch_bounds__(256) void k_contract(const float* __restrict__ ws,
    const unsigned short* __restrict__ wfu, float* __restrict__ accb2) {
  __shared__ float xt[17][44][8];
  int t = blockIdx.x, z = blockIdx.y, k = blockIdx.z, tid = threadIdx.x;
  int I0 = (t >> 2) * 16, J0 = (t & 3) * 16;
  int dylo = -WOFF2 + 2*z;
  int gy0 = I0 + 1 + dylo, gx0 = J0 - 13;
  const float* x66i = ws + 16*QTOT;
  for (int idx = tid; idx < 17*44; idx += 256) {
    int r = idx / 44, cc = idx % 44;
    int gy = gy0 + r, gx = gx0 + cc;
    float4 v0 = make_float4(0.f,0.f,0.f,0.f), v1 = v0;
    if (gy >= 0 && gy < HP && gx >= 0 && gx < HP) {
      const float4* xp = (const float4*)(x66i + (size_t)(gy*HP + gx)*8);
      v0 = xp[0]; v1 = xp[1];
    }
    float4* d = (float4*)&xt[r][cc][0];
    d[0] = v0; d[1] = v1;
  }
  __syncthreads();
  int il = tid >> 4, jl = tid & 15;
  int I = I0 + 1 + il, J = J0 + 1 + jl;
  int pix = I*HP + J;
  int qb = pix >> 3, q7 = pix & 7;
  size_t cb = (((size_t)k*QBN + qb)*NWP)*8 + q7;
  float acc[8];
#pragma unroll
  for (int c = 0; c < 8; ++c) acc[c] = 0.f;
  int ndd = (z == NZ-1) ? 1 : 2;
  for (int dd = 0; dd < ndd; ++dd) {
    int wrow = (dylo + dd + WOFF2) * NWIN;
    const unsigned short* wp = wfu + cb + (size_t)wrow*8;
    unsigned short wv[NWIN];
#pragma unroll
    for (int dxw = 0; dxw < NWIN; ++dxw) wv[dxw] = wp[dxw*8];
    int r = il + dd;
#pragma unroll
    for (int dxw = 0; dxw < NWIN; ++dxw) {
      float wgt = __uint_as_float((unsigned)wv[dxw] << 16);
      const float4* xr = (const float4*)&xt[r][jl + dxw][0];
      float4 x0 = xr[0], x1 = xr[1];
      acc[0] += wgt * x0.x; acc[1] += wgt * x0.y;
      acc[2] += wgt * x0.z; acc[3] += wgt * x0.w;
      acc[4] += wgt * x1.x; acc[5] += wgt * x1.y;
      acc[6] += wgt * x1.z; acc[7] += wgt * x1.w;
    }
  }
  int px64 = (I-1)*64 + (J-1);
#pragma unroll
  for (int c = 0; c < 8; ++c)
    accb2[((z*56 + k*8 + c)*4096) + px64] = acc[c];
}

__global__ __launch_bounds__(256) void k_final(const float* __restrict__ y,
    const float* __restrict__ accb2, float* __restrict__ out) {
  int idx = blockIdx.x * 256 + threadIdx.x;
  int ch = idx >> 12, px = idx & 4095;
  if (ch < 8) { out[idx] = y[ch*4096 + px]; return; }
  int kc = ch - 8, c = kc & 7;
  int i = px >> 6, j = px & 63;
  int I = i + 1, J = j + 1;
  int cy = min(I+5, HP-1) - max(I-4, 0) + 1;
  int cx = min(J+5, HP-1) - max(J-4, 0) + 1;
  float s = 0.f;
  for (int z = 0; z < NZ; ++z) s += accb2[(z*56 + kc)*4096 + px];
  out[idx] = s / (float)(cy*cx) - y[c*4096 + px];
}

extern "C" void kernel_launch(void* const* d_in, const int* in_sizes, int n_in,
                              void* d_out, int out_size, void* d_ws, size_t ws_size,
                              hipStream_t stream) {
  const float* x  = (const float*)d_in[0];
  const float* xe = (const float*)d_in[1];
  const float* ye = (const float*)d_in[2];
  const float* y  = (const float*)d_in[3];
  const float* lt = (const float*)d_in[4];
  float* ws   = (float*)d_ws;
  float* dist = ws + 30*QTOT;
  __hip_bfloat16* wf = (__hip_bfloat16*)(dist + (size_t)NW*QTOT);
  float* accb2 = dist;
  float* out = (float*)d_out;

  k_prep1<<<(QTOT + 255)/256, 256, 0, stream>>>(x, xe, ye, lt, ws);
  k_prep2<<<(QTOT + 255)/256, 256, 0, stream>>>(ws);
  k_dist<<<NW, 256, 0, stream>>>(ws, dist);
  k_weights<<<QBN, 256, 0, stream>>>(ws, dist, wf);
  k_boxw<<<KK*NG, 256, 0, stream>>>(wf);
  k_contract<<<dim3(16, NZ, KK), 256, 0, stream>>>(ws, (const unsigned short*)wf, accb2);
  k_final<<<out_size/256, 256, 0, stream>>>(y, accb2, out);
}

// Round 12
// 160.184 us; speedup vs baseline: 1.0376x; 1.0376x over previous
//
#include <hip/hip_runtime.h>
#include <hip/hip_bf16.h>

#define HP    66
#define QTOT  (HP*HP)          // 4356
#define LSTR  67               // padded LDS row stride
#define NWIN  29
#define NW    (NWIN*NWIN)      // 841
#define NWP   844              // padded w-stride (divisible by 4)
#define NG    211              // NWP/4 groups per k
#define KK    7
#define WOFF2 14
#define NZ    15               // dy-chunks for contraction
#define QB    8                // queries per k_weights block
#define QBN   545              // ceil(QTOT/8)
#define NIT   27               // ceil(841/32)
#define NSEG3 198              // 66 lines x 3 segments of 22

// ws float layout:
// 0        : yex    [QTOT][8] interleaved f32
// 8*QTOT   : xex    [QTOT][8] interleaved f32
// 16*QTOT  : x66i   [QTOT][8] interleaved f32
// 24*QTOT  : sqye   QTOT
// 25*QTOT  : sqxe   QTOT
// 26*QTOT  : lt66   QTOT
// 27*QTOT  : n2q    QTOT
// 28*QTOT  : n2db   QTOT
// 29*QTOT  : ltb    QTOT
// 30*QTOT  : dist   NW*QTOT f32      (reused as accb2 after k_weights)
// 30*QTOT + NW*QTOT : wf  bf16 [k][qb][NWP][8q]

__global__ __launch_bounds__(256) void k_prep1(const float* __restrict__ x,
    const float* __restrict__ xe, const float* __restrict__ ye,
    const float* __restrict__ lt, float* __restrict__ ws) {
  int p = blockIdx.x * 256 + threadIdx.x;
  if (p >= QTOT) return;
  int i = p / HP, j = p % HP;
  bool in = (i >= 1 && i < HP-1 && j >= 1 && j < HP-1);
  int src = (i-1)*64 + (j-1);
  float vy[8], vx[8], vv[8];
  float sy = 0.f, sx = 0.f;
#pragma unroll
  for (int e = 0; e < 8; ++e) {
    vy[e] = in ? ye[e*4096 + src] : 0.f;
    vx[e] = in ? xe[e*4096 + src] : 0.f;
    vv[e] = in ? x [e*4096 + src] : 0.f;
    sy += vy[e]*vy[e]; sx += vx[e]*vx[e];
  }
  float4* yp = (float4*)(ws + (size_t)p*8);
  float4* xp = (float4*)(ws + 8*QTOT + (size_t)p*8);
  float4* vp = (float4*)(ws + 16*QTOT + (size_t)p*8);
  yp[0] = make_float4(vy[0], vy[1], vy[2], vy[3]);
  yp[1] = make_float4(vy[4], vy[5], vy[6], vy[7]);
  xp[0] = make_float4(vx[0], vx[1], vx[2], vx[3]);
  xp[1] = make_float4(vx[4], vx[5], vx[6], vx[7]);
  vp[0] = make_float4(vv[0], vv[1], vv[2], vv[3]);
  vp[1] = make_float4(vv[4], vv[5], vv[6], vv[7]);
  ws[24*QTOT + p] = sy;
  ws[25*QTOT + p] = sx;
  ws[26*QTOT + p] = in ? lt[src] : 0.f;
}

__global__ __launch_bounds__(256) void k_prep2(float* __restrict__ ws) {
  int p = blockIdx.x * 256 + threadIdx.x;
  if (p >= QTOT) return;
  int i = p / HP, j = p % HP;
  const float* sqye = ws + 24*QTOT;
  const float* sqxe = ws + 25*QTOT;
  const float* lt66 = ws + 26*QTOT;
  float a = 0.f, b = 0.f, c = 0.f;
  for (int u = -5; u <= 4; ++u) {
    int ii = i + u; if (ii < 0 || ii >= HP) continue;
    for (int v = -5; v <= 4; ++v) {
      int jj = j + v; if (jj < 0 || jj >= HP) continue;
      int o = ii*HP + jj;
      a += sqye[o]; b += sqxe[o]; c += lt66[o];
    }
  }
  ws[27*QTOT + p] = a;
  ws[28*QTOT + p] = b;
  ws[29*QTOT + p] = c * 0.01f;
}

// one block per shift w: dist plane [w][q]; vectorized interleaved staging;
// register-rotation sliding box [-5,+4]
__global__ __launch_bounds__(256) void k_dist(const float* __restrict__ ws,
                                              float* __restrict__ dist) {
  __shared__ float s[HP*LSTR];
  __shared__ float h[HP*LSTR];
  int w = blockIdx.x, tid = threadIdx.x;
  int dy = w / NWIN - WOFF2, dx = w % NWIN - WOFF2;
  const float* yex = ws;
  const float* xex = ws + 8*QTOT;
  const float* n2q  = ws + 27*QTOT;
  const float* n2db = ws + 28*QTOT;
  for (int p = tid; p < QTOT; p += 256) {
    int i = p / HP, j = p % HP;
    int ii = i + dy, jj = j + dx;
    float sv = 0.f;
    if (ii >= 0 && ii < HP && jj >= 0 && jj < HP) {
      int p2 = ii*HP + jj;
      const float4* yp = (const float4*)(yex + (size_t)p*8);
      const float4* xp = (const float4*)(xex + (size_t)p2*8);
      float4 a0 = yp[0], a1 = yp[1], b0 = xp[0], b1 = xp[1];
      sv += a0.x*b0.x; sv += a0.y*b0.y; sv += a0.z*b0.z; sv += a0.w*b0.w;
      sv += a1.x*b1.x; sv += a1.y*b1.y; sv += a1.z*b1.z; sv += a1.w*b1.w;
    }
    s[i*LSTR + j] = sv;
  }
  __syncthreads();
  if (tid < NSEG3) {
    int row = tid % HP, seg = tid / HP, c0 = seg*22;
    const float* ar = s + row*LSTR;
    float* hr = h + row*LSTR;
    float w9[9]; float sum = 0.f;
#pragma unroll
    for (int t = 0; t < 9; ++t) {
      int jj = c0 - 5 + t;
      float v = (jj >= 0) ? ar[jj] : 0.f;
      w9[t] = v; sum += v;
    }
#pragma unroll
    for (int t = 0; t < 22; ++t) {
      int j = c0 + t, jn = j + 4;
      float nv = (jn < HP) ? ar[jn] : 0.f;
      sum += nv;
      hr[j] = sum;
      sum -= w9[t % 9];
      w9[t % 9] = nv;
    }
  }
  __syncthreads();
  if (tid < NSEG3) {
    int col = tid % HP, seg = tid / HP, r0 = seg*22;
    float w9[9]; float sum = 0.f;
#pragma unroll
    for (int t = 0; t < 9; ++t) {
      int ii = r0 - 5 + t;
      float v = (ii >= 0) ? h[ii*LSTR + col] : 0.f;
      w9[t] = v; sum += v;
    }
#pragma unroll
    for (int t = 0; t < 22; ++t) {
      int i = r0 + t, in2 = i + 4;
      float nv = (in2 < HP) ? h[in2*LSTR + col] : 0.f;
      sum += nv;
      float cr = sum;
      int p = i*HP + col;
      int ii = i + dy, jj = col + dx;
      bool valid = (ii >= 0 && ii < HP && jj >= 0 && jj < HP);
      float dv = 1e10f;
      if (valid && !(dy == 0 && dx == 0))
        dv = n2q[p] + n2db[ii*HP + jj] - 2.f * cr;
      dist[w*QTOT + p] = dv;
      sum -= w9[t % 9];
      w9[t % 9] = nv;
    }
  }
}

// 8 queries/block; lv[] only; writes wf[k][qb][w][8q] (NWP stride),
// zeros the w=841..843 padding columns for determinism
__global__ __launch_bounds__(256) void k_weights(const float* __restrict__ ws,
    const float* __restrict__ dist, __hip_bfloat16* __restrict__ wf) {
  __shared__ float mh[32], sh[32];
  int tid = threadIdx.x;
  int qq = tid & (QB-1);
  int qb = blockIdx.x;
  int q = qb * QB + qq;
  bool qok = q < QTOT;
  int qs = qok ? q : (QTOT - 1);
  int wg = tid >> 3;             // 0..31
  int wave = tid >> 6;           // 0..3
  if (tid < 24) {
    int wp2 = NW + (tid >> 3), q2 = tid & 7;
#pragma unroll
    for (int k = 0; k < KK; ++k)
      wf[(((size_t)k*QBN + qb)*NWP + wp2)*8 + q2] = __float2bfloat16(0.f);
  }
  float invT = __expf(-ws[29*QTOT + qs]);
  float lv[NIT];
#pragma unroll
  for (int it = 0; it < NIT; ++it) {
    int w = wg + it*32;
    lv[it] = (qok && w < NW) ? (-dist[w*QTOT + qs] * invT) : -3.0e38f;
  }
  for (int k = 0; k < KK; ++k) {
    float pm = -3.0e38f;
#pragma unroll
    for (int it = 0; it < NIT; ++it) pm = fmaxf(pm, lv[it]);
    pm = fmaxf(pm, __shfl_xor(pm, 8, 64));
    pm = fmaxf(pm, __shfl_xor(pm, 16, 64));
    pm = fmaxf(pm, __shfl_xor(pm, 32, 64));
    if ((tid & 63) < QB) mh[wave*QB + qq] = pm;
    __syncthreads();
    float m = fmaxf(fmaxf(mh[qq], mh[QB+qq]), fmaxf(mh[2*QB+qq], mh[3*QB+qq]));
    float psum = 0.f;
#pragma unroll
    for (int it = 0; it < NIT; ++it) psum += __expf(lv[it] - m);
    psum += __shfl_xor(psum, 8, 64);
    psum += __shfl_xor(psum, 16, 64);
    psum += __shfl_xor(psum, 32, 64);
    if ((tid & 63) < QB) sh[wave*QB + qq] = psum;
    __syncthreads();
    float invden = 1.0f / (sh[qq] + sh[QB+qq] + sh[2*QB+qq] + sh[3*QB+qq]);
    size_t bkq = ((size_t)k*QBN + qb)*NWP;
#pragma unroll
    for (int it = 0; it < NIT; ++it) {
      int w = wg + it*32;
      if (qok && w < NW) {
        float wgt = __expf(lv[it] - m) * invden;
        wf[(bkq + w)*8 + qq] = __float2bfloat16(wgt);
        if (k < KK-1 && wgt > 1e-9f)
          lv[it] += __logf(fmaxf(1.f - wgt, 1e-6f));
      }
    }
    __syncthreads();
  }
}

// one 256t block per (k, 4-w-group): coalesced 64B-line plane I/O;
// 4 planes box-filtered IN PARALLEL (264 line-tasks over 256 threads),
// both passes IN PLACE in bf16 via register-ring sliding window -> no h
// buffer, 34.9 KB LDS, 2 barriers total
__global__ __launch_bounds__(256) void k_boxw(__hip_bfloat16* __restrict__ wfp) {
  __shared__ uint4 au4[4][546];         // 4 flat bf16[4368] plane stagings
  int bid = blockIdx.x;
  int k = bid / NG, g = bid % NG;
  int w0 = g * 4;
  uint4* u4 = (uint4*)wfp;              // one uint4 = 8 bf16 (one qb fragment)
  size_t pb = ((size_t)k*QBN)*NWP + w0;
  int tid = threadIdx.x;
  // phase 1: line-granular coalesced gather
  for (int idx = tid; idx < QBN*4; idx += 256) {
    int qb = idx >> 2, wl = idx & 3;
    au4[wl][qb] = u4[pb + (size_t)qb*NWP + wl];
  }
  if (tid < 48) {                       // zero junk tail shorts 4356..4367
    int pl = tid / 12, e = tid % 12;
    ((unsigned short*)au4[pl])[4356 + e] = 0;
  }
  __syncthreads();
  // h-pass, window [-4,+5], IN PLACE (ring holds trailing originals)
  for (int task = tid; task < 4*HP; task += 256) {
    int pl = task & 3, row = task >> 2;
    unsigned short* ar = (unsigned short*)au4[pl] + row*HP;
    float w9[9]; float sum = 0.f;
#pragma unroll
    for (int t = 0; t < 9; ++t) {
      int jj = t - 4;
      float v = (jj >= 0) ? __uint_as_float((unsigned)ar[jj] << 16) : 0.f;
      w9[t] = v; sum += v;
    }
#pragma unroll
    for (int j = 0; j < HP; ++j) {
      float nv = (j + 5 < HP) ? __uint_as_float((unsigned)ar[j+5] << 16) : 0.f;
      sum += nv;
      ar[j] = __bfloat16_as_ushort(__float2bfloat16(sum));
      sum -= w9[j % 9];
      w9[j % 9] = nv;
    }
  }
  __syncthreads();
  // v-pass, window [-4,+5], IN PLACE
  for (int task = tid; task < 4*HP; task += 256) {
    int pl = task & 3, col = task >> 2;
    unsigned short* ac = (unsigned short*)au4[pl] + col;
    float w9[9]; float sum = 0.f;
#pragma unroll
    for (int t = 0; t < 9; ++t) {
      int ii = t - 4;
      float v = (ii >= 0) ? __uint_as_float((unsigned)ac[ii*HP] << 16) : 0.f;
      w9[t] = v; sum += v;
    }
#pragma unroll
    for (int i = 0; i < HP; ++i) {
      float nv = (i + 5 < HP) ? __uint_as_float((unsigned)ac[(i+5)*HP] << 16) : 0.f;
      sum += nv;
      ac[i*HP] = __bfloat16_as_ushort(__float2bfloat16(sum));
      sum -= w9[i % 9];
      w9[i % 9] = nv;
    }
  }
  __syncthreads();
  // phase 4: coalesced scatter back
  for (int idx = tid; idx < QBN*4; idx += 256) {
    int qb = idx >> 2, wl = idx & 3;
    u4[pb + (size_t)qb*NWP + wl] = au4[wl][qb];
  }
}

// grid (16 tiles, NZ, KK): per dd-row, 29 batched ushort loads with immediate
// offsets, then 29 x (2 ds_read_b128 + 8 FMA); xt [r][cc][8] c-contiguous
__global__ __launch_bounds__(256) void k_contract(const float* __restrict__ ws,
    const unsigned short* __restrict__ wfu, float* __restrict__ accb2) {
  __shared__ float xt[17][44][8];
  int t = blockIdx.x, z = blockIdx.y, k = blockIdx.z, tid = threadIdx.x;
  int I0 = (t >> 2) * 16, J0 = (t & 3) * 16;
  int dylo = -WOFF2 + 2*z;
  int gy0 = I0 + 1 + dylo, gx0 = J0 - 13;
  const float* x66i = ws + 16*QTOT;
  for (int idx = tid; idx < 17*44; idx += 256) {
    int r = idx / 44, cc = idx % 44;
    int gy = gy0 + r, gx = gx0 + cc;
    float4 v0 = make_float4(0.f,0.f,0.f,0.f), v1 = v0;
    if (gy >= 0 && gy < HP && gx >= 0 && gx < HP) {
      const float4* xp = (const float4*)(x66i + (size_t)(gy*HP + gx)*8);
      v0 = xp[0]; v1 = xp[1];
    }
    float4* d = (float4*)&xt[r][cc][0];
    d[0] = v0; d[1] = v1;
  }
  __syncthreads();
  int il = tid >> 4, jl = tid & 15;
  int I = I0 + 1 + il, J = J0 + 1 + jl;
  int pix = I*HP + J;
  int qb = pix >> 3, q7 = pix & 7;
  size_t cb = (((size_t)k*QBN + qb)*NWP)*8 + q7;
  float acc[8];
#pragma unroll
  for (int c = 0; c < 8; ++c) acc[c] = 0.f;
  int ndd = (z == NZ-1) ? 1 : 2;
  for (int dd = 0; dd < ndd; ++dd) {
    int wrow = (dylo + dd + WOFF2) * NWIN;
    const unsigned short* wp = wfu + cb + (size_t)wrow*8;
    unsigned short wv[NWIN];
#pragma unroll
    for (int dxw = 0; dxw < NWIN; ++dxw) wv[dxw] = wp[dxw*8];
    int r = il + dd;
#pragma unroll
    for (int dxw = 0; dxw < NWIN; ++dxw) {
      float wgt = __uint_as_float((unsigned)wv[dxw] << 16);
      const float4* xr = (const float4*)&xt[r][jl + dxw][0];
      float4 x0 = xr[0], x1 = xr[1];
      acc[0] += wgt * x0.x; acc[1] += wgt * x0.y;
      acc[2] += wgt * x0.z; acc[3] += wgt * x0.w;
      acc[4] += wgt * x1.x; acc[5] += wgt * x1.y;
      acc[6] += wgt * x1.z; acc[7] += wgt * x1.w;
    }
  }
  int px64 = (I-1)*64 + (J-1);
#pragma unroll
  for (int c = 0; c < 8; ++c)
    accb2[((z*56 + k*8 + c)*4096) + px64] = acc[c];
}

__global__ __launch_bounds__(256) void k_final(const float* __restrict__ y,
    const float* __restrict__ accb2, float* __restrict__ out) {
  int idx = blockIdx.x * 256 + threadIdx.x;
  int ch = idx >> 12, px = idx & 4095;
  if (ch < 8) { out[idx] = y[ch*4096 + px]; return; }
  int kc = ch - 8, c = kc & 7;
  int i = px >> 6, j = px & 63;
  int I = i + 1, J = j + 1;
  int cy = min(I+5, HP-1) - max(I-4, 0) + 1;
  int cx = min(J+5, HP-1) - max(J-4, 0) + 1;
  float s = 0.f;
  for (int z = 0; z < NZ; ++z) s += accb2[(z*56 + kc)*4096 + px];
  out[idx] = s / (float)(cy*cx) - y[c*4096 + px];
}

extern "C" void kernel_launch(void* const* d_in, const int* in_sizes, int n_in,
                              void* d_out, int out_size, void* d_ws, size_t ws_size,
                              hipStream_t stream) {
  const float* x  = (const float*)d_in[0];
  const float* xe = (const float*)d_in[1];
  const float* ye = (const float*)d_in[2];
  const float* y  = (const float*)d_in[3];
  const float* lt = (const float*)d_in[4];
  float* ws   = (float*)d_ws;
  float* dist = ws + 30*QTOT;
  __hip_bfloat16* wf = (__hip_bfloat16*)(dist + (size_t)NW*QTOT);
  float* accb2 = dist;
  float* out = (float*)d_out;

  k_prep1<<<(QTOT + 255)/256, 256, 0, stream>>>(x, xe, ye, lt, ws);
  k_prep2<<<(QTOT + 255)/256, 256, 0, stream>>>(ws);
  k_dist<<<NW, 256, 0, stream>>>(ws, dist);
  k_weights<<<QBN, 256, 0, stream>>>(ws, dist, wf);
  k_boxw<<<KK*NG, 256, 0, stream>>>(wf);
  k_contract<<<dim3(16, NZ, KK), 256, 0, stream>>>(ws, (const unsigned short*)wf, accb2);
  k_final<<<out_size/256, 256, 0, stream>>>(y, accb2, out);
}

// Round 13
// 147.623 us; speedup vs baseline: 1.1259x; 1.0851x over previous
//
#include <hip/hip_runtime.h>
#include <hip/hip_bf16.h>

#define HP    66
#define QTOT  (HP*HP)          // 4356
#define LSTR  67               // padded LDS row stride
#define NWIN  29
#define NW    (NWIN*NWIN)      // 841
#define KK    7
#define WOFF2 14
#define NZ    15               // dy-chunks for contraction
#define QB    8                // queries per k_weights block
#define QBN   545              // ceil(QTOT/8)
#define NIT   27               // ceil(841/32)
#define NSEG3 198              // 66 lines x 3 segments of 22 (k_dist)

// ws float layout:
// 0        : yex    [QTOT][8] interleaved f32
// 8*QTOT   : xex    [QTOT][8] interleaved f32
// 16*QTOT  : x66i   [QTOT][8] interleaved f32
// 24*QTOT  : sqye   QTOT
// 25*QTOT  : sqxe   QTOT
// 26*QTOT  : lt66   QTOT
// 27*QTOT  : n2q    QTOT
// 28*QTOT  : n2db   QTOT
// 29*QTOT  : ltb    QTOT
// 30*QTOT  : dist   NW*QTOT f32      (reused as accb2 after k_weights)
// 30*QTOT + NW*QTOT : wf  bf16 [k][qb][w][8q]

__global__ __launch_bounds__(256) void k_prep1(const float* __restrict__ x,
    const float* __restrict__ xe, const float* __restrict__ ye,
    const float* __restrict__ lt, float* __restrict__ ws) {
  int p = blockIdx.x * 256 + threadIdx.x;
  if (p >= QTOT) return;
  int i = p / HP, j = p % HP;
  bool in = (i >= 1 && i < HP-1 && j >= 1 && j < HP-1);
  int src = (i-1)*64 + (j-1);
  float vy[8], vx[8], vv[8];
  float sy = 0.f, sx = 0.f;
#pragma unroll
  for (int e = 0; e < 8; ++e) {
    vy[e] = in ? ye[e*4096 + src] : 0.f;
    vx[e] = in ? xe[e*4096 + src] : 0.f;
    vv[e] = in ? x [e*4096 + src] : 0.f;
    sy += vy[e]*vy[e]; sx += vx[e]*vx[e];
  }
  float4* yp = (float4*)(ws + (size_t)p*8);
  float4* xp = (float4*)(ws + 8*QTOT + (size_t)p*8);
  float4* vp = (float4*)(ws + 16*QTOT + (size_t)p*8);
  yp[0] = make_float4(vy[0], vy[1], vy[2], vy[3]);
  yp[1] = make_float4(vy[4], vy[5], vy[6], vy[7]);
  xp[0] = make_float4(vx[0], vx[1], vx[2], vx[3]);
  xp[1] = make_float4(vx[4], vx[5], vx[6], vx[7]);
  vp[0] = make_float4(vv[0], vv[1], vv[2], vv[3]);
  vp[1] = make_float4(vv[4], vv[5], vv[6], vv[7]);
  ws[24*QTOT + p] = sy;
  ws[25*QTOT + p] = sx;
  ws[26*QTOT + p] = in ? lt[src] : 0.f;
}

__global__ __launch_bounds__(256) void k_prep2(float* __restrict__ ws) {
  int p = blockIdx.x * 256 + threadIdx.x;
  if (p >= QTOT) return;
  int i = p / HP, j = p % HP;
  const float* sqye = ws + 24*QTOT;
  const float* sqxe = ws + 25*QTOT;
  const float* lt66 = ws + 26*QTOT;
  float a = 0.f, b = 0.f, c = 0.f;
  for (int u = -5; u <= 4; ++u) {
    int ii = i + u; if (ii < 0 || ii >= HP) continue;
    for (int v = -5; v <= 4; ++v) {
      int jj = j + v; if (jj < 0 || jj >= HP) continue;
      int o = ii*HP + jj;
      a += sqye[o]; b += sqxe[o]; c += lt66[o];
    }
  }
  ws[27*QTOT + p] = a;
  ws[28*QTOT + p] = b;
  ws[29*QTOT + p] = c * 0.01f;
}

// one block per shift w: dist plane [w][q]; vectorized interleaved staging;
// register-rotation sliding box [-5,+4]
__global__ __launch_bounds__(256) void k_dist(const float* __restrict__ ws,
                                              float* __restrict__ dist) {
  __shared__ float s[HP*LSTR];
  __shared__ float h[HP*LSTR];
  int w = blockIdx.x, tid = threadIdx.x;
  int dy = w / NWIN - WOFF2, dx = w % NWIN - WOFF2;
  const float* yex = ws;
  const float* xex = ws + 8*QTOT;
  const float* n2q  = ws + 27*QTOT;
  const float* n2db = ws + 28*QTOT;
  for (int p = tid; p < QTOT; p += 256) {
    int i = p / HP, j = p % HP;
    int ii = i + dy, jj = j + dx;
    float sv = 0.f;
    if (ii >= 0 && ii < HP && jj >= 0 && jj < HP) {
      int p2 = ii*HP + jj;
      const float4* yp = (const float4*)(yex + (size_t)p*8);
      const float4* xp = (const float4*)(xex + (size_t)p2*8);
      float4 a0 = yp[0], a1 = yp[1], b0 = xp[0], b1 = xp[1];
      sv += a0.x*b0.x; sv += a0.y*b0.y; sv += a0.z*b0.z; sv += a0.w*b0.w;
      sv += a1.x*b1.x; sv += a1.y*b1.y; sv += a1.z*b1.z; sv += a1.w*b1.w;
    }
    s[i*LSTR + j] = sv;
  }
  __syncthreads();
  if (tid < NSEG3) {
    int row = tid % HP, seg = tid / HP, c0 = seg*22;
    const float* ar = s + row*LSTR;
    float* hr = h + row*LSTR;
    float w9[9]; float sum = 0.f;
#pragma unroll
    for (int t = 0; t < 9; ++t) {
      int jj = c0 - 5 + t;
      float v = (jj >= 0) ? ar[jj] : 0.f;
      w9[t] = v; sum += v;
    }
#pragma unroll
    for (int t = 0; t < 22; ++t) {
      int j = c0 + t, jn = j + 4;
      float nv = (jn < HP) ? ar[jn] : 0.f;
      sum += nv;
      hr[j] = sum;
      sum -= w9[t % 9];
      w9[t % 9] = nv;
    }
  }
  __syncthreads();
  if (tid < NSEG3) {
    int col = tid % HP, seg = tid / HP, r0 = seg*22;
    float w9[9]; float sum = 0.f;
#pragma unroll
    for (int t = 0; t < 9; ++t) {
      int ii = r0 - 5 + t;
      float v = (ii >= 0) ? h[ii*LSTR + col] : 0.f;
      w9[t] = v; sum += v;
    }
#pragma unroll
    for (int t = 0; t < 22; ++t) {
      int i = r0 + t, in2 = i + 4;
      float nv = (in2 < HP) ? h[in2*LSTR + col] : 0.f;
      sum += nv;
      float cr = sum;
      int p = i*HP + col;
      int ii = i + dy, jj = col + dx;
      bool valid = (ii >= 0 && ii < HP && jj >= 0 && jj < HP);
      float dv = 1e10f;
      if (valid && !(dy == 0 && dx == 0))
        dv = n2q[p] + n2db[ii*HP + jj] - 2.f * cr;
      dist[w*QTOT + p] = dv;
      sum -= w9[t % 9];
      w9[t % 9] = nv;
    }
  }
}

// 8 queries/block; lv[] only; writes wf[k][qb][w][8q] -> 128B/wave stores
__global__ __launch_bounds__(256) void k_weights(const float* __restrict__ ws,
    const float* __restrict__ dist, __hip_bfloat16* __restrict__ wf) {
  __shared__ float mh[32], sh[32];
  int tid = threadIdx.x;
  int qq = tid & (QB-1);
  int qb = blockIdx.x;
  int q = qb * QB + qq;
  bool qok = q < QTOT;
  int qs = qok ? q : (QTOT - 1);
  int wg = tid >> 3;             // 0..31
  int wave = tid >> 6;           // 0..3
  float invT = __expf(-ws[29*QTOT + qs]);
  float lv[NIT];
#pragma unroll
  for (int it = 0; it < NIT; ++it) {
    int w = wg + it*32;
    lv[it] = (qok && w < NW) ? (-dist[w*QTOT + qs] * invT) : -3.0e38f;
  }
  for (int k = 0; k < KK; ++k) {
    float pm = -3.0e38f;
#pragma unroll
    for (int it = 0; it < NIT; ++it) pm = fmaxf(pm, lv[it]);
    pm = fmaxf(pm, __shfl_xor(pm, 8, 64));
    pm = fmaxf(pm, __shfl_xor(pm, 16, 64));
    pm = fmaxf(pm, __shfl_xor(pm, 32, 64));
    if ((tid & 63) < QB) mh[wave*QB + qq] = pm;
    __syncthreads();
    float m = fmaxf(fmaxf(mh[qq], mh[QB+qq]), fmaxf(mh[2*QB+qq], mh[3*QB+qq]));
    float psum = 0.f;
#pragma unroll
    for (int it = 0; it < NIT; ++it) psum += __expf(lv[it] - m);
    psum += __shfl_xor(psum, 8, 64);
    psum += __shfl_xor(psum, 16, 64);
    psum += __shfl_xor(psum, 32, 64);
    if ((tid & 63) < QB) sh[wave*QB + qq] = psum;
    __syncthreads();
    float invden = 1.0f / (sh[qq] + sh[QB+qq] + sh[2*QB+qq] + sh[3*QB+qq]);
    size_t bkq = ((size_t)k*QBN + qb)*NW;
#pragma unroll
    for (int it = 0; it < NIT; ++it) {
      int w = wg + it*32;
      if (qok && w < NW) {
        float wgt = __expf(lv[it] - m) * invden;
        wf[(bkq + w)*8 + qq] = __float2bfloat16(wgt);
        if (k < KK-1 && wgt > 1e-9f)
          lv[it] += __logf(fmaxf(1.f - wgt, 1e-6f));
      }
    }
    __syncthreads();
  }
}

// one 256t block per (k,w) plane (XCD swizzle: adjacent w -> same XCD L2,
// which absorbs the 16B-strided line sharing — proven R8: FETCH 25MB,
// WRITE 50MB no amplification). Flat bf16 staging a + flat bf16 h buffer
// (17.5KB LDS -> 8 blocks/CU = 32 waves = 100% occupancy); both passes
// 6-way segmented (chains of 11); race-free: h-pass a->h, v-pass h->a.
__global__ __launch_bounds__(256) void k_boxw(__hip_bfloat16* __restrict__ wfp) {
  __shared__ uint4 au4[546];            // flat bf16[4368]
  __shared__ uint4 hu4[546];            // flat bf16[4368] intermediate
  int bid = blockIdx.x;
  int l = (bid & 7)*736 + (bid >> 3);   // bijective on 0..5886
  if (l >= KK*NW) return;
  int k = l / NW, w = l % NW;
  uint4* u4 = (uint4*)wfp;              // one uint4 = 8 bf16 (one qb fragment)
  size_t pb = ((size_t)k*QBN)*NW + w;
  int tid = threadIdx.x;
  for (int qb = tid; qb < QBN; qb += 256)
    au4[qb] = u4[pb + (size_t)qb*NW];
  if (tid < 12) ((unsigned short*)au4)[4356 + tid] = 0;  // tail determinism
  __syncthreads();
  const unsigned short* a16 = (const unsigned short*)au4;
  unsigned short* h16 = (unsigned short*)hu4;
  // h-pass, window [-4,+5]: 66 rows x 6 segments of 11
  for (int task = tid; task < 396; task += 256) {
    int row = task % HP, seg = task / HP, c0 = seg*11;
    const unsigned short* ar = a16 + row*HP;
    unsigned short* hr = h16 + row*HP;
    float w9[9]; float sum = 0.f;
#pragma unroll
    for (int t = 0; t < 9; ++t) {
      int jj = c0 - 4 + t;                      // <= c0+4 <= 59 < HP
      float v = (jj >= 0) ? __uint_as_float((unsigned)ar[jj] << 16) : 0.f;
      w9[t] = v; sum += v;
    }
#pragma unroll
    for (int t = 0; t < 11; ++t) {
      int j = c0 + t, jn = j + 5;
      float nv = (jn < HP) ? __uint_as_float((unsigned)ar[jn] << 16) : 0.f;
      sum += nv;
      hr[j] = __bfloat16_as_ushort(__float2bfloat16(sum));
      sum -= w9[t % 9];
      w9[t % 9] = nv;
    }
  }
  __syncthreads();
  unsigned short* a16w = (unsigned short*)au4;
  // v-pass, window [-4,+5]: 66 cols x 6 segments of 11; writes back into a
  for (int task = tid; task < 396; task += 256) {
    int col = task % HP, seg = task / HP, r0 = seg*11;
    float w9[9]; float sum = 0.f;
#pragma unroll
    for (int t = 0; t < 9; ++t) {
      int ii = r0 - 4 + t;
      float v = (ii >= 0) ? __uint_as_float((unsigned)h16[ii*HP + col] << 16) : 0.f;
      w9[t] = v; sum += v;
    }
#pragma unroll
    for (int t = 0; t < 11; ++t) {
      int i = r0 + t, in2 = i + 5;
      float nv = (in2 < HP) ? __uint_as_float((unsigned)h16[in2*HP + col] << 16) : 0.f;
      sum += nv;
      a16w[i*HP + col] = __bfloat16_as_ushort(__float2bfloat16(sum));
      sum -= w9[t % 9];
      w9[t % 9] = nv;
    }
  }
  __syncthreads();
  for (int qb = tid; qb < QBN; qb += 256)
    u4[pb + (size_t)qb*NW] = au4[qb];
}

// grid (16 tiles, NZ, KK): per dd-row, 29 batched ushort loads with immediate
// offsets, then 29 x (2 ds_read_b128 + 8 FMA); xt [r][cc][8] c-contiguous
__global__ __launch_bounds__(256) void k_contract(const float* __restrict__ ws,
    const unsigned short* __restrict__ wfu, float* __restrict__ accb2) {
  __shared__ float xt[17][44][8];
  int t = blockIdx.x, z = blockIdx.y, k = blockIdx.z, tid = threadIdx.x;
  int I0 = (t >> 2) * 16, J0 = (t & 3) * 16;
  int dylo = -WOFF2 + 2*z;
  int gy0 = I0 + 1 + dylo, gx0 = J0 - 13;
  const float* x66i = ws + 16*QTOT;
  for (int idx = tid; idx < 17*44; idx += 256) {
    int r = idx / 44, cc = idx % 44;
    int gy = gy0 + r, gx = gx0 + cc;
    float4 v0 = make_float4(0.f,0.f,0.f,0.f), v1 = v0;
    if (gy >= 0 && gy < HP && gx >= 0 && gx < HP) {
      const float4* xp = (const float4*)(x66i + (size_t)(gy*HP + gx)*8);
      v0 = xp[0]; v1 = xp[1];
    }
    float4* d = (float4*)&xt[r][cc][0];
    d[0] = v0; d[1] = v1;
  }
  __syncthreads();
  int il = tid >> 4, jl = tid & 15;
  int I = I0 + 1 + il, J = J0 + 1 + jl;
  int pix = I*HP + J;
  int qb = pix >> 3, q7 = pix & 7;
  size_t cb = (((size_t)k*QBN + qb)*NW)*8 + q7;
  float acc[8];
#pragma unroll
  for (int c = 0; c < 8; ++c) acc[c] = 0.f;
  int ndd = (z == NZ-1) ? 1 : 2;
  for (int dd = 0; dd < ndd; ++dd) {
    int wrow = (dylo + dd + WOFF2) * NWIN;
    const unsigned short* wp = wfu + cb + (size_t)wrow*8;
    unsigned short wv[NWIN];
#pragma unroll
    for (int dxw = 0; dxw < NWIN; ++dxw) wv[dxw] = wp[dxw*8];
    int r = il + dd;
#pragma unroll
    for (int dxw = 0; dxw < NWIN; ++dxw) {
      float wgt = __uint_as_float((unsigned)wv[dxw] << 16);
      const float4* xr = (const float4*)&xt[r][jl + dxw][0];
      float4 x0 = xr[0], x1 = xr[1];
      acc[0] += wgt * x0.x; acc[1] += wgt * x0.y;
      acc[2] += wgt * x0.z; acc[3] += wgt * x0.w;
      acc[4] += wgt * x1.x; acc[5] += wgt * x1.y;
      acc[6] += wgt * x1.z; acc[7] += wgt * x1.w;
    }
  }
  int px64 = (I-1)*64 + (J-1);
#pragma unroll
  for (int c = 0; c < 8; ++c)
    accb2[((z*56 + k*8 + c)*4096) + px64] = acc[c];
}

__global__ __launch_bounds__(256) void k_final(const float* __restrict__ y,
    const float* __restrict__ accb2, float* __restrict__ out) {
  int idx = blockIdx.x * 256 + threadIdx.x;
  int ch = idx >> 12, px = idx & 4095;
  if (ch < 8) { out[idx] = y[ch*4096 + px]; return; }
  int kc = ch - 8, c = kc & 7;
  int i = px >> 6, j = px & 63;
  int I = i + 1, J = j + 1;
  int cy = min(I+5, HP-1) - max(I-4, 0) + 1;
  int cx = min(J+5, HP-1) - max(J-4, 0) + 1;
  float s = 0.f;
  for (int z = 0; z < NZ; ++z) s += accb2[(z*56 + kc)*4096 + px];
  out[idx] = s / (float)(cy*cx) - y[c*4096 + px];
}

extern "C" void kernel_launch(void* const* d_in, const int* in_sizes, int n_in,
                              void* d_out, int out_size, void* d_ws, size_t ws_size,
                              hipStream_t stream) {
  const float* x  = (const float*)d_in[0];
  const float* xe = (const float*)d_in[1];
  const float* ye = (const float*)d_in[2];
  const float* y  = (const float*)d_in[3];
  const float* lt = (const float*)d_in[4];
  float* ws   = (float*)d_ws;
  float* dist = ws + 30*QTOT;
  __hip_bfloat16* wf = (__hip_bfloat16*)(dist + (size_t)NW*QTOT);
  float* accb2 = dist;
  float* out = (float*)d_out;

  k_prep1<<<(QTOT + 255)/256, 256, 0, stream>>>(x, xe, ye, lt, ws);
  k_prep2<<<(QTOT + 255)/256, 256, 0, stream>>>(ws);
  k_dist<<<NW, 256, 0, stream>>>(ws, dist);
  k_weights<<<QBN, 256, 0, stream>>>(ws, dist, wf);
  k_boxw<<<KK*NW, 256, 0, stream>>>(wf);
  k_contract<<<dim3(16, NZ, KK), 256, 0, stream>>>(ws, (const unsigned short*)wf, accb2);
  k_final<<<out_size/256, 256, 0, stream>>>(y, accb2, out);
}

// Round 14
// 145.304 us; speedup vs baseline: 1.1439x; 1.0160x over previous
//
#include <hip/hip_runtime.h>
#include <hip/hip_bf16.h>

#define HP    66
#define QTOT  (HP*HP)          // 4356
#define NWIN  29
#define NW    (NWIN*NWIN)      // 841
#define KK    7
#define WOFF2 14
#define NZ    15               // dy-chunks for contraction
#define QB    8                // queries per k_weights block
#define QBN   545              // ceil(QTOT/8)
#define NIT   27               // ceil(841/32)
#define NSEG3 198              // 66 lines x 3 segments of 22 (k_dist)
#define PSTR  4368             // wfB plane stride in u16 (546 uint4)

// ws float layout:
// 0        : yex    [QTOT][8] interleaved f32
// 8*QTOT   : xex    [QTOT][8] interleaved f32
// 16*QTOT  : x66i   [QTOT][8] interleaved f32
// 24*QTOT  : sqye/sqxe/lt66/n2q/n2db/ltb  (6 x QTOT)
// 30*QTOT  : dist   NW*QTOT f32 [w][q]   (reused as accb2 after k_weights)
// + NW*QTOT: wfA bf16 [k][qb][w][8q]     (weights -> boxw gather)
// + KK*QBN*NW*8 u16: wfB bf16 [k][w][PSTR]  (boxw -> contract, coalesced)

__global__ __launch_bounds__(256) void k_prep1(const float* __restrict__ x,
    const float* __restrict__ xe, const float* __restrict__ ye,
    const float* __restrict__ lt, float* __restrict__ ws) {
  int p = blockIdx.x * 256 + threadIdx.x;
  if (p >= QTOT) return;
  int i = p / HP, j = p % HP;
  bool in = (i >= 1 && i < HP-1 && j >= 1 && j < HP-1);
  int src = (i-1)*64 + (j-1);
  float vy[8], vx[8], vv[8];
  float sy = 0.f, sx = 0.f;
#pragma unroll
  for (int e = 0; e < 8; ++e) {
    vy[e] = in ? ye[e*4096 + src] : 0.f;
    vx[e] = in ? xe[e*4096 + src] : 0.f;
    vv[e] = in ? x [e*4096 + src] : 0.f;
    sy += vy[e]*vy[e]; sx += vx[e]*vx[e];
  }
  float4* yp = (float4*)(ws + (size_t)p*8);
  float4* xp = (float4*)(ws + 8*QTOT + (size_t)p*8);
  float4* vp = (float4*)(ws + 16*QTOT + (size_t)p*8);
  yp[0] = make_float4(vy[0], vy[1], vy[2], vy[3]);
  yp[1] = make_float4(vy[4], vy[5], vy[6], vy[7]);
  xp[0] = make_float4(vx[0], vx[1], vx[2], vx[3]);
  xp[1] = make_float4(vx[4], vx[5], vx[6], vx[7]);
  vp[0] = make_float4(vv[0], vv[1], vv[2], vv[3]);
  vp[1] = make_float4(vv[4], vv[5], vv[6], vv[7]);
  ws[24*QTOT + p] = sy;
  ws[25*QTOT + p] = sx;
  ws[26*QTOT + p] = in ? lt[src] : 0.f;
}

__global__ __launch_bounds__(256) void k_prep2(float* __restrict__ ws) {
  int p = blockIdx.x * 256 + threadIdx.x;
  if (p >= QTOT) return;
  int i = p / HP, j = p % HP;
  const float* sqye = ws + 24*QTOT;
  const float* sqxe = ws + 25*QTOT;
  const float* lt66 = ws + 26*QTOT;
  float a = 0.f, b = 0.f, c = 0.f;
  for (int u = -5; u <= 4; ++u) {
    int ii = i + u; if (ii < 0 || ii >= HP) continue;
    for (int v = -5; v <= 4; ++v) {
      int jj = j + v; if (jj < 0 || jj >= HP) continue;
      int o = ii*HP + jj;
      a += sqye[o]; b += sqxe[o]; c += lt66[o];
    }
  }
  ws[27*QTOT + p] = a;
  ws[28*QTOT + p] = b;
  ws[29*QTOT + p] = c * 0.01f;
}

// one block per shift w: dist plane [w][q]; flat LDS; register-rotation box
// [-5,+4]; dv staged in LDS then stored as coalesced float4 bursts
__global__ __launch_bounds__(256) void k_dist(const float* __restrict__ ws,
                                              float* __restrict__ dist) {
  __shared__ float4 s4[QTOT/4];         // flat f32[QTOT], 16B aligned
  __shared__ float h[QTOT];
  float* s = (float*)s4;
  int w = blockIdx.x, tid = threadIdx.x;
  int dy = w / NWIN - WOFF2, dx = w % NWIN - WOFF2;
  const float* yex = ws;
  const float* xex = ws + 8*QTOT;
  const float* n2q  = ws + 27*QTOT;
  const float* n2db = ws + 28*QTOT;
  for (int p = tid; p < QTOT; p += 256) {
    int i = p / HP, j = p % HP;
    int ii = i + dy, jj = j + dx;
    float sv = 0.f;
    if (ii >= 0 && ii < HP && jj >= 0 && jj < HP) {
      int p2 = ii*HP + jj;
      const float4* yp = (const float4*)(yex + (size_t)p*8);
      const float4* xp = (const float4*)(xex + (size_t)p2*8);
      float4 a0 = yp[0], a1 = yp[1], b0 = xp[0], b1 = xp[1];
      sv += a0.x*b0.x; sv += a0.y*b0.y; sv += a0.z*b0.z; sv += a0.w*b0.w;
      sv += a1.x*b1.x; sv += a1.y*b1.y; sv += a1.z*b1.z; sv += a1.w*b1.w;
    }
    s[p] = sv;
  }
  __syncthreads();
  if (tid < NSEG3) {                    // h-pass, window [-5,+4]
    int row = tid % HP, seg = tid / HP, c0 = seg*22;
    const float* ar = s + row*HP;
    float* hr = h + row*HP;
    float w9[9]; float sum = 0.f;
#pragma unroll
    for (int t = 0; t < 9; ++t) {
      int jj = c0 - 5 + t;
      float v = (jj >= 0) ? ar[jj] : 0.f;
      w9[t] = v; sum += v;
    }
#pragma unroll
    for (int t = 0; t < 22; ++t) {
      int j = c0 + t, jn = j + 4;
      float nv = (jn < HP) ? ar[jn] : 0.f;
      sum += nv;
      hr[j] = sum;
      sum -= w9[t % 9];
      w9[t % 9] = nv;
    }
  }
  __syncthreads();
  if (tid < NSEG3) {                    // v-pass [-5,+4] + dist epilogue -> s
    int col = tid % HP, seg = tid / HP, r0 = seg*22;
    float w9[9]; float sum = 0.f;
#pragma unroll
    for (int t = 0; t < 9; ++t) {
      int ii = r0 - 5 + t;
      float v = (ii >= 0) ? h[ii*HP + col] : 0.f;
      w9[t] = v; sum += v;
    }
#pragma unroll
    for (int t = 0; t < 22; ++t) {
      int i = r0 + t, in2 = i + 4;
      float nv = (in2 < HP) ? h[in2*HP + col] : 0.f;
      sum += nv;
      float cr = sum;
      int p = i*HP + col;
      int ii = i + dy, jj = col + dx;
      bool valid = (ii >= 0 && ii < HP && jj >= 0 && jj < HP);
      float dv = 1e10f;
      if (valid && !(dy == 0 && dx == 0))
        dv = n2q[p] + n2db[ii*HP + jj] - 2.f * cr;
      s[p] = dv;                        // s dead after h-pass; no race
      sum -= w9[t % 9];
      w9[t % 9] = nv;
    }
  }
  __syncthreads();
  float4* dq = (float4*)(dist + (size_t)w*QTOT);
  for (int p4 = tid; p4 < QTOT/4; p4 += 256)   // coalesced store
    dq[p4] = s4[p4];
}

// 8 queries/block; lv[] only; writes wfA[k][qb][w][8q] -> 128B/wave stores
__global__ __launch_bounds__(256) void k_weights(const float* __restrict__ ws,
    const float* __restrict__ dist, __hip_bfloat16* __restrict__ wf) {
  __shared__ float mh[32], sh[32];
  int tid = threadIdx.x;
  int qq = tid & (QB-1);
  int qb = blockIdx.x;
  int q = qb * QB + qq;
  bool qok = q < QTOT;
  int qs = qok ? q : (QTOT - 1);
  int wg = tid >> 3;             // 0..31
  int wave = tid >> 6;           // 0..3
  float invT = __expf(-ws[29*QTOT + qs]);
  float lv[NIT];
#pragma unroll
  for (int it = 0; it < NIT; ++it) {
    int w = wg + it*32;
    lv[it] = (qok && w < NW) ? (-dist[w*QTOT + qs] * invT) : -3.0e38f;
  }
  for (int k = 0; k < KK; ++k) {
    float pm = -3.0e38f;
#pragma unroll
    for (int it = 0; it < NIT; ++it) pm = fmaxf(pm, lv[it]);
    pm = fmaxf(pm, __shfl_xor(pm, 8, 64));
    pm = fmaxf(pm, __shfl_xor(pm, 16, 64));
    pm = fmaxf(pm, __shfl_xor(pm, 32, 64));
    if ((tid & 63) < QB) mh[wave*QB + qq] = pm;
    __syncthreads();
    float m = fmaxf(fmaxf(mh[qq], mh[QB+qq]), fmaxf(mh[2*QB+qq], mh[3*QB+qq]));
    float psum = 0.f;
#pragma unroll
    for (int it = 0; it < NIT; ++it) psum += __expf(lv[it] - m);
    psum += __shfl_xor(psum, 8, 64);
    psum += __shfl_xor(psum, 16, 64);
    psum += __shfl_xor(psum, 32, 64);
    if ((tid & 63) < QB) sh[wave*QB + qq] = psum;
    __syncthreads();
    float invden = 1.0f / (sh[qq] + sh[QB+qq] + sh[2*QB+qq] + sh[3*QB+qq]);
    size_t bkq = ((size_t)k*QBN + qb)*NW;
#pragma unroll
    for (int it = 0; it < NIT; ++it) {
      int w = wg + it*32;
      if (qok && w < NW) {
        float wgt = __expf(lv[it] - m) * invden;
        wf[(bkq + w)*8 + qq] = __float2bfloat16(wgt);
        if (k < KK-1 && wgt > 1e-9f)
          lv[it] += __logf(fmaxf(1.f - wgt, 1e-6f));
      }
    }
    __syncthreads();
  }
}

// one 256t block per (k,w) plane (XCD swizzle for gather L2 line-sharing).
// Gather scattered from wfA[k][qb][w][8q]; box in flat bf16 LDS (17.5KB,
// 8 blocks/CU); STORE COALESCED to wfB[k][w][PSTR] (546 contiguous uint4).
__global__ __launch_bounds__(256) void k_boxw(const __hip_bfloat16* __restrict__ wfa,
                                              __hip_bfloat16* __restrict__ wfb) {
  __shared__ uint4 au4[546];            // flat bf16[4368]
  __shared__ uint4 hu4[546];            // flat bf16[4368] intermediate
  int bid = blockIdx.x;
  int l = (bid & 7)*736 + (bid >> 3);   // bijective on 0..5886
  if (l >= KK*NW) return;
  int k = l / NW, w = l % NW;
  const uint4* u4 = (const uint4*)wfa;
  size_t pb = ((size_t)k*QBN)*NW + w;
  int tid = threadIdx.x;
  for (int qb = tid; qb < QBN; qb += 256)
    au4[qb] = u4[pb + (size_t)qb*NW];
  if (tid < 12) ((unsigned short*)au4)[4356 + tid] = 0;  // tail determinism
  __syncthreads();
  const unsigned short* a16 = (const unsigned short*)au4;
  unsigned short* h16 = (unsigned short*)hu4;
  // h-pass, window [-4,+5]: 66 rows x 6 segments of 11
  for (int task = tid; task < 396; task += 256) {
    int row = task % HP, seg = task / HP, c0 = seg*11;
    const unsigned short* ar = a16 + row*HP;
    unsigned short* hr = h16 + row*HP;
    float w9[9]; float sum = 0.f;
#pragma unroll
    for (int t = 0; t < 9; ++t) {
      int jj = c0 - 4 + t;
      float v = (jj >= 0) ? __uint_as_float((unsigned)ar[jj] << 16) : 0.f;
      w9[t] = v; sum += v;
    }
#pragma unroll
    for (int t = 0; t < 11; ++t) {
      int j = c0 + t, jn = j + 5;
      float nv = (jn < HP) ? __uint_as_float((unsigned)ar[jn] << 16) : 0.f;
      sum += nv;
      hr[j] = __bfloat16_as_ushort(__float2bfloat16(sum));
      sum -= w9[t % 9];
      w9[t % 9] = nv;
    }
  }
  __syncthreads();
  unsigned short* a16w = (unsigned short*)au4;
  // v-pass, window [-4,+5]: 66 cols x 6 segments of 11; writes back into a
  for (int task = tid; task < 396; task += 256) {
    int col = task % HP, seg = task / HP, r0 = seg*11;
    float w9[9]; float sum = 0.f;
#pragma unroll
    for (int t = 0; t < 9; ++t) {
      int ii = r0 - 4 + t;
      float v = (ii >= 0) ? __uint_as_float((unsigned)h16[ii*HP + col] << 16) : 0.f;
      w9[t] = v; sum += v;
    }
#pragma unroll
    for (int t = 0; t < 11; ++t) {
      int i = r0 + t, in2 = i + 5;
      float nv = (in2 < HP) ? __uint_as_float((unsigned)h16[in2*HP + col] << 16) : 0.f;
      sum += nv;
      a16w[i*HP + col] = __bfloat16_as_ushort(__float2bfloat16(sum));
      sum -= w9[t % 9];
      w9[t % 9] = nv;
    }
  }
  __syncthreads();
  uint4* out4 = (uint4*)(wfb + ((size_t)k*NW + w)*PSTR);
  for (int qb = tid; qb < 546; qb += 256)     // fully coalesced plane store
    out4[qb] = au4[qb];
}

// grid (16 tiles, NZ, KK): per dd-row, 29 batched u16 loads from wfB planes,
// then 29 x (2 ds_read_b128 + 8 FMA); xt [r][cc][8] c-contiguous
__global__ __launch_bounds__(256) void k_contract(const float* __restrict__ ws,
    const unsigned short* __restrict__ wfb, float* __restrict__ accb2) {
  __shared__ float xt[17][44][8];
  int t = blockIdx.x, z = blockIdx.y, k = blockIdx.z, tid = threadIdx.x;
  int I0 = (t >> 2) * 16, J0 = (t & 3) * 16;
  int dylo = -WOFF2 + 2*z;
  int gy0 = I0 + 1 + dylo, gx0 = J0 - 13;
  const float* x66i = ws + 16*QTOT;
  for (int idx = tid; idx < 17*44; idx += 256) {
    int r = idx / 44, cc = idx % 44;
    int gy = gy0 + r, gx = gx0 + cc;
    float4 v0 = make_float4(0.f,0.f,0.f,0.f), v1 = v0;
    if (gy >= 0 && gy < HP && gx >= 0 && gx < HP) {
      const float4* xp = (const float4*)(x66i + (size_t)(gy*HP + gx)*8);
      v0 = xp[0]; v1 = xp[1];
    }
    float4* d = (float4*)&xt[r][cc][0];
    d[0] = v0; d[1] = v1;
  }
  __syncthreads();
  int il = tid >> 4, jl = tid & 15;
  int I = I0 + 1 + il, J = J0 + 1 + jl;
  int pix = I*HP + J;
  float acc[8];
#pragma unroll
  for (int c = 0; c < 8; ++c) acc[c] = 0.f;
  int ndd = (z == NZ-1) ? 1 : 2;
  for (int dd = 0; dd < ndd; ++dd) {
    int wrow = (dylo + dd + WOFF2) * NWIN;
    const unsigned short* wp = wfb + ((size_t)k*NW + wrow)*PSTR + pix;
    unsigned short wv[NWIN];
#pragma unroll
    for (int dxw = 0; dxw < NWIN; ++dxw) wv[dxw] = wp[(size_t)dxw*PSTR];
    int r = il + dd;
#pragma unroll
    for (int dxw = 0; dxw < NWIN; ++dxw) {
      float wgt = __uint_as_float((unsigned)wv[dxw] << 16);
      const float4* xr = (const float4*)&xt[r][jl + dxw][0];
      float4 x0 = xr[0], x1 = xr[1];
      acc[0] += wgt * x0.x; acc[1] += wgt * x0.y;
      acc[2] += wgt * x0.z; acc[3] += wgt * x0.w;
      acc[4] += wgt * x1.x; acc[5] += wgt * x1.y;
      acc[6] += wgt * x1.z; acc[7] += wgt * x1.w;
    }
  }
  int px64 = (I-1)*64 + (J-1);
#pragma unroll
  for (int c = 0; c < 8; ++c)
    accb2[((z*56 + k*8 + c)*4096) + px64] = acc[c];
}

__global__ __launch_bounds__(256) void k_final(const float* __restrict__ y,
    const float* __restrict__ accb2, float* __restrict__ out) {
  int idx = blockIdx.x * 256 + threadIdx.x;
  int ch = idx >> 12, px = idx & 4095;
  if (ch < 8) { out[idx] = y[ch*4096 + px]; return; }
  int kc = ch - 8, c = kc & 7;
  int i = px >> 6, j = px & 63;
  int I = i + 1, J = j + 1;
  int cy = min(I+5, HP-1) - max(I-4, 0) + 1;
  int cx = min(J+5, HP-1) - max(J-4, 0) + 1;
  float s = 0.f;
  for (int z = 0; z < NZ; ++z) s += accb2[(z*56 + kc)*4096 + px];
  out[idx] = s / (float)(cy*cx) - y[c*4096 + px];
}

extern "C" void kernel_launch(void* const* d_in, const int* in_sizes, int n_in,
                              void* d_out, int out_size, void* d_ws, size_t ws_size,
                              hipStream_t stream) {
  const float* x  = (const float*)d_in[0];
  const float* xe = (const float*)d_in[1];
  const float* ye = (const float*)d_in[2];
  const float* y  = (const float*)d_in[3];
  const float* lt = (const float*)d_in[4];
  float* ws   = (float*)d_ws;
  float* dist = ws + 30*QTOT;
  __hip_bfloat16* wfa = (__hip_bfloat16*)(dist + (size_t)NW*QTOT);
  __hip_bfloat16* wfb = wfa + (size_t)KK*QBN*NW*8;
  float* accb2 = dist;
  float* out = (float*)d_out;

  k_prep1<<<(QTOT + 255)/256, 256, 0, stream>>>(x, xe, ye, lt, ws);
  k_prep2<<<(QTOT + 255)/256, 256, 0, stream>>>(ws);
  k_dist<<<NW, 256, 0, stream>>>(ws, dist);
  k_weights<<<QBN, 256, 0, stream>>>(ws, dist, wfa);
  k_boxw<<<KK*NW, 256, 0, stream>>>(wfa, wfb);
  k_contract<<<dim3(16, NZ, KK), 256, 0, stream>>>(ws, (const unsigned short*)wfb, accb2);
  k_final<<<out_size/256, 256, 0, stream>>>(y, accb2, out);
}

// Round 15
// 144.356 us; speedup vs baseline: 1.1514x; 1.0066x over previous
//
#include <hip/hip_runtime.h>
#include <hip/hip_bf16.h>

#define HP    66
#define QTOT  (HP*HP)          // 4356
#define NWIN  29
#define NW    (NWIN*NWIN)      // 841
#define KK    7
#define WOFF2 14
#define NZ    15               // dy-chunks for contraction
#define QB    8                // queries per k_weights block
#define QBN   545              // ceil(QTOT/8)
#define NIT   27               // ceil(841/32)
#define NSEG3 198              // 66 lines x 3 segments of 22 (k_dist)
#define PSTR  4368             // wf plane stride in u16 (546 uint4)

// ws float layout:
// 0        : yex    [QTOT][8] interleaved f32
// 8*QTOT   : xex    [QTOT][8] interleaved f32
// 16*QTOT  : x66i   [QTOT][8] interleaved f32
// 24*QTOT  : sqye/sqxe/lt66/n2q/n2db/ltb  (6 x QTOT)
// 30*QTOT  : dist   NW*QTOT f32 [w][q]   (reused as accb2 after k_weights)
// + NW*QTOT: wf bf16 [k][w][PSTR]  (weights scatter-write -> boxw in-place
//            coalesced -> contract read)

__global__ __launch_bounds__(256) void k_prep1(const float* __restrict__ x,
    const float* __restrict__ xe, const float* __restrict__ ye,
    const float* __restrict__ lt, float* __restrict__ ws) {
  int p = blockIdx.x * 256 + threadIdx.x;
  if (p >= QTOT) return;
  int i = p / HP, j = p % HP;
  bool in = (i >= 1 && i < HP-1 && j >= 1 && j < HP-1);
  int src = (i-1)*64 + (j-1);
  float vy[8], vx[8], vv[8];
  float sy = 0.f, sx = 0.f;
#pragma unroll
  for (int e = 0; e < 8; ++e) {
    vy[e] = in ? ye[e*4096 + src] : 0.f;
    vx[e] = in ? xe[e*4096 + src] : 0.f;
    vv[e] = in ? x [e*4096 + src] : 0.f;
    sy += vy[e]*vy[e]; sx += vx[e]*vx[e];
  }
  float4* yp = (float4*)(ws + (size_t)p*8);
  float4* xp = (float4*)(ws + 8*QTOT + (size_t)p*8);
  float4* vp = (float4*)(ws + 16*QTOT + (size_t)p*8);
  yp[0] = make_float4(vy[0], vy[1], vy[2], vy[3]);
  yp[1] = make_float4(vy[4], vy[5], vy[6], vy[7]);
  xp[0] = make_float4(vx[0], vx[1], vx[2], vx[3]);
  xp[1] = make_float4(vx[4], vx[5], vx[6], vx[7]);
  vp[0] = make_float4(vv[0], vv[1], vv[2], vv[3]);
  vp[1] = make_float4(vv[4], vv[5], vv[6], vv[7]);
  ws[24*QTOT + p] = sy;
  ws[25*QTOT + p] = sx;
  ws[26*QTOT + p] = in ? lt[src] : 0.f;
}

__global__ __launch_bounds__(256) void k_prep2(float* __restrict__ ws) {
  int p = blockIdx.x * 256 + threadIdx.x;
  if (p >= QTOT) return;
  int i = p / HP, j = p % HP;
  const float* sqye = ws + 24*QTOT;
  const float* sqxe = ws + 25*QTOT;
  const float* lt66 = ws + 26*QTOT;
  float a = 0.f, b = 0.f, c = 0.f;
  for (int u = -5; u <= 4; ++u) {
    int ii = i + u; if (ii < 0 || ii >= HP) continue;
    for (int v = -5; v <= 4; ++v) {
      int jj = j + v; if (jj < 0 || jj >= HP) continue;
      int o = ii*HP + jj;
      a += sqye[o]; b += sqxe[o]; c += lt66[o];
    }
  }
  ws[27*QTOT + p] = a;
  ws[28*QTOT + p] = b;
  ws[29*QTOT + p] = c * 0.01f;
}

// one block per shift w: dist plane [w][q]; flat LDS; register-rotation box
// [-5,+4]; dv staged in LDS then stored as coalesced float4 bursts
__global__ __launch_bounds__(256) void k_dist(const float* __restrict__ ws,
                                              float* __restrict__ dist) {
  __shared__ float4 s4[QTOT/4];         // flat f32[QTOT], 16B aligned
  __shared__ float h[QTOT];
  float* s = (float*)s4;
  int w = blockIdx.x, tid = threadIdx.x;
  int dy = w / NWIN - WOFF2, dx = w % NWIN - WOFF2;
  const float* yex = ws;
  const float* xex = ws + 8*QTOT;
  const float* n2q  = ws + 27*QTOT;
  const float* n2db = ws + 28*QTOT;
  for (int p = tid; p < QTOT; p += 256) {
    int i = p / HP, j = p % HP;
    int ii = i + dy, jj = j + dx;
    float sv = 0.f;
    if (ii >= 0 && ii < HP && jj >= 0 && jj < HP) {
      int p2 = ii*HP + jj;
      const float4* yp = (const float4*)(yex + (size_t)p*8);
      const float4* xp = (const float4*)(xex + (size_t)p2*8);
      float4 a0 = yp[0], a1 = yp[1], b0 = xp[0], b1 = xp[1];
      sv += a0.x*b0.x; sv += a0.y*b0.y; sv += a0.z*b0.z; sv += a0.w*b0.w;
      sv += a1.x*b1.x; sv += a1.y*b1.y; sv += a1.z*b1.z; sv += a1.w*b1.w;
    }
    s[p] = sv;
  }
  __syncthreads();
  if (tid < NSEG3) {                    // h-pass, window [-5,+4]
    int row = tid % HP, seg = tid / HP, c0 = seg*22;
    const float* ar = s + row*HP;
    float* hr = h + row*HP;
    float w9[9]; float sum = 0.f;
#pragma unroll
    for (int t = 0; t < 9; ++t) {
      int jj = c0 - 5 + t;
      float v = (jj >= 0) ? ar[jj] : 0.f;
      w9[t] = v; sum += v;
    }
#pragma unroll
    for (int t = 0; t < 22; ++t) {
      int j = c0 + t, jn = j + 4;
      float nv = (jn < HP) ? ar[jn] : 0.f;
      sum += nv;
      hr[j] = sum;
      sum -= w9[t % 9];
      w9[t % 9] = nv;
    }
  }
  __syncthreads();
  if (tid < NSEG3) {                    // v-pass [-5,+4] + dist epilogue -> s
    int col = tid % HP, seg = tid / HP, r0 = seg*22;
    float w9[9]; float sum = 0.f;
#pragma unroll
    for (int t = 0; t < 9; ++t) {
      int ii = r0 - 5 + t;
      float v = (ii >= 0) ? h[ii*HP + col] : 0.f;
      w9[t] = v; sum += v;
    }
#pragma unroll
    for (int t = 0; t < 22; ++t) {
      int i = r0 + t, in2 = i + 4;
      float nv = (in2 < HP) ? h[in2*HP + col] : 0.f;
      sum += nv;
      float cr = sum;
      int p = i*HP + col;
      int ii = i + dy, jj = col + dx;
      bool valid = (ii >= 0 && ii < HP && jj >= 0 && jj < HP);
      float dv = 1e10f;
      if (valid && !(dy == 0 && dx == 0))
        dv = n2q[p] + n2db[ii*HP + jj] - 2.f * cr;
      s[p] = dv;                        // s dead after h-pass; no race
      sum -= w9[t % 9];
      w9[t % 9] = nv;
    }
  }
  __syncthreads();
  float4* dq = (float4*)(dist + (size_t)w*QTOT);
  for (int p4 = tid; p4 < QTOT/4; p4 += 256)   // coalesced store
    dq[p4] = s4[p4];
}

// 8 queries/block (qb XCD-swizzled so the 4 blocks sharing each 64B output
// line co-reside on one XCD -> L2 write-merge, R8 precedent); lv[] only;
// writes DIRECTLY into wf[k][w][PSTR] (scattered 16B stores, non-blocking)
__global__ __launch_bounds__(256) void k_weights(const float* __restrict__ ws,
    const float* __restrict__ dist, __hip_bfloat16* __restrict__ wf) {
  __shared__ float mh[32], sh[32];
  int tid = threadIdx.x;
  int bid = blockIdx.x;                 // 545 blocks; m204 bijection (68,r=1)
  int xcd = bid & 7, idx = bid >> 3;
  int qb = (xcd == 0) ? idx : (69 + (xcd-1)*68 + idx);
  int qq = tid & (QB-1);
  int q = qb * QB + qq;
  bool qok = q < QTOT;
  int qs = qok ? q : (QTOT - 1);
  int wg = tid >> 3;             // 0..31
  int wave = tid >> 6;           // 0..3
  float invT = __expf(-ws[29*QTOT + qs]);
  float lv[NIT];
#pragma unroll
  for (int it = 0; it < NIT; ++it) {
    int w = wg + it*32;
    lv[it] = (qok && w < NW) ? (-dist[w*QTOT + qs] * invT) : -3.0e38f;
  }
  for (int k = 0; k < KK; ++k) {
    float pm = -3.0e38f;
#pragma unroll
    for (int it = 0; it < NIT; ++it) pm = fmaxf(pm, lv[it]);
    pm = fmaxf(pm, __shfl_xor(pm, 8, 64));
    pm = fmaxf(pm, __shfl_xor(pm, 16, 64));
    pm = fmaxf(pm, __shfl_xor(pm, 32, 64));
    if ((tid & 63) < QB) mh[wave*QB + qq] = pm;
    __syncthreads();
    float m = fmaxf(fmaxf(mh[qq], mh[QB+qq]), fmaxf(mh[2*QB+qq], mh[3*QB+qq]));
    float psum = 0.f;
#pragma unroll
    for (int it = 0; it < NIT; ++it) psum += __expf(lv[it] - m);
    psum += __shfl_xor(psum, 8, 64);
    psum += __shfl_xor(psum, 16, 64);
    psum += __shfl_xor(psum, 32, 64);
    if ((tid & 63) < QB) sh[wave*QB + qq] = psum;
    __syncthreads();
    float invden = 1.0f / (sh[qq] + sh[QB+qq] + sh[2*QB+qq] + sh[3*QB+qq]);
    size_t kbase = (size_t)k*NW*PSTR + q;
#pragma unroll
    for (int it = 0; it < NIT; ++it) {
      int w = wg + it*32;
      if (qok && w < NW) {
        float wgt = __expf(lv[it] - m) * invden;
        wf[kbase + (size_t)w*PSTR] = __float2bfloat16(wgt);
        if (k < KK-1 && wgt > 1e-9f)
          lv[it] += __logf(fmaxf(1.f - wgt, 1e-6f));
      }
    }
    __syncthreads();
  }
}

// one 256t block per (k,w) plane: FULLY COALESCED in-place plane load/store
// (546 contiguous uint4); box in flat bf16 LDS (17.5KB -> 8 blocks/CU);
// both passes 6-way segmented (chains of 11); race-free: a->h, h->a.
__global__ __launch_bounds__(256) void k_boxw(__hip_bfloat16* __restrict__ wfp) {
  __shared__ uint4 au4[546];            // flat bf16[4368]
  __shared__ uint4 hu4[546];            // flat bf16[4368] intermediate
  int bid = blockIdx.x;                 // 0..KK*NW-1
  uint4* plane = (uint4*)(wfp + (size_t)bid*PSTR);
  int tid = threadIdx.x;
  for (int qb = tid; qb < 546; qb += 256)
    au4[qb] = plane[qb];
  __syncthreads();
  const unsigned short* a16 = (const unsigned short*)au4;
  unsigned short* h16 = (unsigned short*)hu4;
  // h-pass, window [-4,+5]: 66 rows x 6 segments of 11
  for (int task = tid; task < 396; task += 256) {
    int row = task % HP, seg = task / HP, c0 = seg*11;
    const unsigned short* ar = a16 + row*HP;
    unsigned short* hr = h16 + row*HP;
    float w9[9]; float sum = 0.f;
#pragma unroll
    for (int t = 0; t < 9; ++t) {
      int jj = c0 - 4 + t;
      float v = (jj >= 0) ? __uint_as_float((unsigned)ar[jj] << 16) : 0.f;
      w9[t] = v; sum += v;
    }
#pragma unroll
    for (int t = 0; t < 11; ++t) {
      int j = c0 + t, jn = j + 5;
      float nv = (jn < HP) ? __uint_as_float((unsigned)ar[jn] << 16) : 0.f;
      sum += nv;
      hr[j] = __bfloat16_as_ushort(__float2bfloat16(sum));
      sum -= w9[t % 9];
      w9[t % 9] = nv;
    }
  }
  __syncthreads();
  unsigned short* a16w = (unsigned short*)au4;
  // v-pass, window [-4,+5]: 66 cols x 6 segments of 11; writes back into a
  for (int task = tid; task < 396; task += 256) {
    int col = task % HP, seg = task / HP, r0 = seg*11;
    float w9[9]; float sum = 0.f;
#pragma unroll
    for (int t = 0; t < 9; ++t) {
      int ii = r0 - 4 + t;
      float v = (ii >= 0) ? __uint_as_float((unsigned)h16[ii*HP + col] << 16) : 0.f;
      w9[t] = v; sum += v;
    }
#pragma unroll
    for (int t = 0; t < 11; ++t) {
      int i = r0 + t, in2 = i + 5;
      float nv = (in2 < HP) ? __uint_as_float((unsigned)h16[in2*HP + col] << 16) : 0.f;
      sum += nv;
      a16w[i*HP + col] = __bfloat16_as_ushort(__float2bfloat16(sum));
      sum -= w9[t % 9];
      w9[t % 9] = nv;
    }
  }
  __syncthreads();
  for (int qb = tid; qb < 546; qb += 256)     // coalesced in-place store
    plane[qb] = au4[qb];
}

// grid (16 tiles, NZ, KK): per dd-row, 29 batched u16 loads from wf planes,
// then 29 x (2 ds_read_b128 + 8 FMA); xt [r][cc][8] c-contiguous
__global__ __launch_bounds__(256) void k_contract(const float* __restrict__ ws,
    const unsigned short* __restrict__ wfb, float* __restrict__ accb2) {
  __shared__ float xt[17][44][8];
  int t = blockIdx.x, z = blockIdx.y, k = blockIdx.z, tid = threadIdx.x;
  int I0 = (t >> 2) * 16, J0 = (t & 3) * 16;
  int dylo = -WOFF2 + 2*z;
  int gy0 = I0 + 1 + dylo, gx0 = J0 - 13;
  const float* x66i = ws + 16*QTOT;
  for (int idx = tid; idx < 17*44; idx += 256) {
    int r = idx / 44, cc = idx % 44;
    int gy = gy0 + r, gx = gx0 + cc;
    float4 v0 = make_float4(0.f,0.f,0.f,0.f), v1 = v0;
    if (gy >= 0 && gy < HP && gx >= 0 && gx < HP) {
      const float4* xp = (const float4*)(x66i + (size_t)(gy*HP + gx)*8);
      v0 = xp[0]; v1 = xp[1];
    }
    float4* d = (float4*)&xt[r][cc][0];
    d[0] = v0; d[1] = v1;
  }
  __syncthreads();
  int il = tid >> 4, jl = tid & 15;
  int I = I0 + 1 + il, J = J0 + 1 + jl;
  int pix = I*HP + J;
  float acc[8];
#pragma unroll
  for (int c = 0; c < 8; ++c) acc[c] = 0.f;
  int ndd = (z == NZ-1) ? 1 : 2;
  for (int dd = 0; dd < ndd; ++dd) {
    int wrow = (dylo + dd + WOFF2) * NWIN;
    const unsigned short* wp = wfb + ((size_t)k*NW + wrow)*PSTR + pix;
    unsigned short wv[NWIN];
#pragma unroll
    for (int dxw = 0; dxw < NWIN; ++dxw) wv[dxw] = wp[(size_t)dxw*PSTR];
    int r = il + dd;
#pragma unroll
    for (int dxw = 0; dxw < NWIN; ++dxw) {
      float wgt = __uint_as_float((unsigned)wv[dxw] << 16);
      const float4* xr = (const float4*)&xt[r][jl + dxw][0];
      float4 x0 = xr[0], x1 = xr[1];
      acc[0] += wgt * x0.x; acc[1] += wgt * x0.y;
      acc[2] += wgt * x0.z; acc[3] += wgt * x0.w;
      acc[4] += wgt * x1.x; acc[5] += wgt * x1.y;
      acc[6] += wgt * x1.z; acc[7] += wgt * x1.w;
    }
  }
  int px64 = (I-1)*64 + (J-1);
#pragma unroll
  for (int c = 0; c < 8; ++c)
    accb2[((z*56 + k*8 + c)*4096) + px64] = acc[c];
}

__global__ __launch_bounds__(256) void k_final(const float* __restrict__ y,
    const float* __restrict__ accb2, float* __restrict__ out) {
  int idx = blockIdx.x * 256 + threadIdx.x;
  int ch = idx >> 12, px = idx & 4095;
  if (ch < 8) { out[idx] = y[ch*4096 + px]; return; }
  int kc = ch - 8, c = kc & 7;
  int i = px >> 6, j = px & 63;
  int I = i + 1, J = j + 1;
  int cy = min(I+5, HP-1) - max(I-4, 0) + 1;
  int cx = min(J+5, HP-1) - max(J-4, 0) + 1;
  float s = 0.f;
  for (int z = 0; z < NZ; ++z) s += accb2[(z*56 + kc)*4096 + px];
  out[idx] = s / (float)(cy*cx) - y[c*4096 + px];
}

extern "C" void kernel_launch(void* const* d_in, const int* in_sizes, int n_in,
                              void* d_out, int out_size, void* d_ws, size_t ws_size,
                              hipStream_t stream) {
  const float* x  = (const float*)d_in[0];
  const float* xe = (const float*)d_in[1];
  const float* ye = (const float*)d_in[2];
  const float* y  = (const float*)d_in[3];
  const float* lt = (const float*)d_in[4];
  float* ws   = (float*)d_ws;
  float* dist = ws + 30*QTOT;
  __hip_bfloat16* wf = (__hip_bfloat16*)(dist + (size_t)NW*QTOT);
  float* accb2 = dist;
  float* out = (float*)d_out;

  k_prep1<<<(QTOT + 255)/256, 256, 0, stream>>>(x, xe, ye, lt, ws);
  k_prep2<<<(QTOT + 255)/256, 256, 0, stream>>>(ws);
  k_dist<<<NW, 256, 0, stream>>>(ws, dist);
  k_weights<<<QBN, 256, 0, stream>>>(ws, dist, wf);
  k_boxw<<<KK*NW, 256, 0, stream>>>(wf);
  k_contract<<<dim3(16, NZ, KK), 256, 0, stream>>>(ws, (const unsigned short*)wf, accb2);
  k_final<<<out_size/256, 256, 0, stream>>>(y, accb2, out);
}